// Round 2
// baseline (415.244 us; speedup 1.0000x reference)
//
#include <hip/hip_runtime.h>
#include <stdint.h>

// ---------------- problem constants ----------------
#define B2      192          // 16 * MAX_FRAMES
#define NTOK    50           // tokens per frame-batch
#define ROWS    9600         // B2 * NTOK
#define D_EMB   512
#define C_DIM   256
#define HD      128          // head dim
#define NSAMP   500
#define TOPKK   12
#define NSPA    48           // 50 - SEL_DIM

__device__ __forceinline__ float gelu_f(float x) {
    return 0.5f * x * (1.0f + erff(x * 0.7071067811865476f));
}

// ---------------- LayerNorm: one wave per row of 512 ----------------
__global__ __launch_bounds__(256) void ln_kernel(const float* __restrict__ x,
                                                 const float* __restrict__ g,
                                                 const float* __restrict__ b,
                                                 float* __restrict__ xn) {
    int row  = blockIdx.x * 4 + (threadIdx.x >> 6);
    int lane = threadIdx.x & 63;
    const float* rp = x + (size_t)row * D_EMB;
    float4 v0 = *(const float4*)(rp + lane * 8);
    float4 v1 = *(const float4*)(rp + lane * 8 + 4);
    float s  = v0.x + v0.y + v0.z + v0.w + v1.x + v1.y + v1.z + v1.w;
    float s2 = v0.x*v0.x + v0.y*v0.y + v0.z*v0.z + v0.w*v0.w
             + v1.x*v1.x + v1.y*v1.y + v1.z*v1.z + v1.w*v1.w;
#pragma unroll
    for (int off = 32; off; off >>= 1) {
        s  += __shfl_xor(s,  off);
        s2 += __shfl_xor(s2, off);
    }
    float mu  = s / 512.0f;
    float var = s2 / 512.0f - mu * mu;
    float inv = 1.0f / sqrtf(var + 1e-5f);
    float* op = xn + (size_t)row * D_EMB;
    const float* gp = g + lane * 8;
    const float* bp = b + lane * 8;
    float4 o0, o1;
    o0.x = (v0.x - mu) * inv * gp[0] + bp[0];
    o0.y = (v0.y - mu) * inv * gp[1] + bp[1];
    o0.z = (v0.z - mu) * inv * gp[2] + bp[2];
    o0.w = (v0.w - mu) * inv * gp[3] + bp[3];
    o1.x = (v1.x - mu) * inv * gp[4] + bp[4];
    o1.y = (v1.y - mu) * inv * gp[5] + bp[5];
    o1.z = (v1.z - mu) * inv * gp[6] + bp[6];
    o1.w = (v1.w - mu) * inv * gp[7] + bp[7];
    *(float4*)(op + lane * 8)     = o0;
    *(float4*)(op + lane * 8 + 4) = o1;
}

// ---------------- fp32 tiled GEMM: C[M,N] = act(A[M,K] @ W[K,N] + bias) ----------------
// 64x64 tile, 256 threads, 4x4 per thread. M%64==0, N%64==0, K%16==0 assumed.
// bias (if non-null) is indexed [ (row/50)*N + col ]  (the mean-pool concat trick).
__global__ __launch_bounds__(256) void gemm_f32(const float* __restrict__ A,
                                                const float* __restrict__ W,
                                                float* __restrict__ C,
                                                int M, int N, int K,
                                                const float* __restrict__ bias,
                                                int act) {
    __shared__ float As[16][68];  // [k][m], padded
    __shared__ float Ws[16][64];  // [k][n]
    int m0 = blockIdx.x * 64, n0 = blockIdx.y * 64;
    int tid = threadIdx.x;
    int tm = tid >> 4, tn = tid & 15;
    int lr = tid >> 2, lc = (tid & 3) * 4;   // A-load: row 0..63, k 0..15
    int wr = tid >> 4, wc = (tid & 15) * 4;  // W-load: k 0..15, col 0..63
    float acc[4][4] = {};
    for (int k0 = 0; k0 < K; k0 += 16) {
        float4 av = *(const float4*)(A + (size_t)(m0 + lr) * K + k0 + lc);
        float4 wv = *(const float4*)(W + (size_t)(k0 + wr) * N + n0 + wc);
        __syncthreads();
        As[lc + 0][lr] = av.x; As[lc + 1][lr] = av.y;
        As[lc + 2][lr] = av.z; As[lc + 3][lr] = av.w;
        *(float4*)&Ws[wr][wc] = wv;
        __syncthreads();
#pragma unroll
        for (int kk = 0; kk < 16; ++kk) {
            float4 a = *(const float4*)&As[kk][tm * 4];
            float4 b = *(const float4*)&Ws[kk][tn * 4];
            acc[0][0] = fmaf(a.x, b.x, acc[0][0]); acc[0][1] = fmaf(a.x, b.y, acc[0][1]);
            acc[0][2] = fmaf(a.x, b.z, acc[0][2]); acc[0][3] = fmaf(a.x, b.w, acc[0][3]);
            acc[1][0] = fmaf(a.y, b.x, acc[1][0]); acc[1][1] = fmaf(a.y, b.y, acc[1][1]);
            acc[1][2] = fmaf(a.y, b.z, acc[1][2]); acc[1][3] = fmaf(a.y, b.w, acc[1][3]);
            acc[2][0] = fmaf(a.z, b.x, acc[2][0]); acc[2][1] = fmaf(a.z, b.y, acc[2][1]);
            acc[2][2] = fmaf(a.z, b.z, acc[2][2]); acc[2][3] = fmaf(a.z, b.w, acc[2][3]);
            acc[3][0] = fmaf(a.w, b.x, acc[3][0]); acc[3][1] = fmaf(a.w, b.y, acc[3][1]);
            acc[3][2] = fmaf(a.w, b.z, acc[3][2]); acc[3][3] = fmaf(a.w, b.w, acc[3][3]);
        }
    }
#pragma unroll
    for (int i = 0; i < 4; ++i) {
        int r = m0 + tm * 4 + i;
        int c0 = n0 + tn * 4;
        float4 o;
        float* po = &o.x;
#pragma unroll
        for (int j = 0; j < 4; ++j) {
            float v = acc[i][j];
            if (bias) v += bias[(size_t)(r / 50) * N + c0 + j];
            if (act) v = gelu_f(v);
            po[j] = v;
        }
        *(float4*)(C + (size_t)r * N + c0) = o;
    }
}

// ---------------- attention: one block per (batch, head) ----------------
__global__ __launch_bounds__(256) void attn_kernel(const float* __restrict__ q,
                                                   const float* __restrict__ k,
                                                   const float* __restrict__ v,
                                                   float* __restrict__ ao) {
    __shared__ float sQ[NTOK * 132];  // q, later v (row stride 132 to break bank conflicts)
    __shared__ float sK[NTOK * 132];
    __shared__ float sS[NTOK * 51];
    int blk = blockIdx.x;
    int b = blk >> 1, h = blk & 1;
    const size_t base = (size_t)b * NTOK * C_DIM + h * HD;
    int tid = threadIdx.x;
    for (int idx = tid; idx < 1600; idx += 256) {
        int r = idx >> 5, c = (idx & 31) * 4;
        *(float4*)&sQ[r * 132 + c] = *(const float4*)(q + base + (size_t)r * C_DIM + c);
        *(float4*)&sK[r * 132 + c] = *(const float4*)(k + base + (size_t)r * C_DIM + c);
    }
    __syncthreads();
    for (int e = tid; e < NTOK * NTOK; e += 256) {
        int i = e / NTOK, j = e - i * NTOK;
        const float* qi = &sQ[i * 132];
        const float* kj = &sK[j * 132];
        float4 acc = {0.f, 0.f, 0.f, 0.f};
#pragma unroll
        for (int t = 0; t < 32; ++t) {
            float4 a = *(const float4*)&qi[t * 4];
            float4 bb = *(const float4*)&kj[t * 4];
            acc.x = fmaf(a.x, bb.x, acc.x); acc.y = fmaf(a.y, bb.y, acc.y);
            acc.z = fmaf(a.z, bb.z, acc.z); acc.w = fmaf(a.w, bb.w, acc.w);
        }
        sS[i * 51 + j] = (acc.x + acc.y + acc.z + acc.w) * 0.08838834764831845f; // 1/sqrt(128)
    }
    __syncthreads();
    // overwrite sQ with v; softmax rows in parallel
    for (int idx = tid; idx < 1600; idx += 256) {
        int r = idx >> 5, c = (idx & 31) * 4;
        *(float4*)&sQ[r * 132 + c] = *(const float4*)(v + base + (size_t)r * C_DIM + c);
    }
    if (tid < NTOK) {
        float* row = &sS[tid * 51];
        float m = row[0];
        for (int j = 1; j < NTOK; ++j) m = fmaxf(m, row[j]);
        float sum = 0.f;
        for (int j = 0; j < NTOK; ++j) { float e2 = expf(row[j] - m); row[j] = e2; sum += e2; }
        float inv = 1.0f / sum;
        for (int j = 0; j < NTOK; ++j) row[j] *= inv;
    }
    __syncthreads();
    for (int e = tid; e < NTOK * HD; e += 256) {
        int i = e >> 7, d = e & 127;
        const float* srow = &sS[i * 51];
        float acc = 0.f;
#pragma unroll
        for (int j = 0; j < NTOK; ++j) acc = fmaf(srow[j], sQ[j * 132 + d], acc);
        ao[base + (size_t)i * C_DIM + d] = acc;
    }
}

// ---------------- mean over the 50 tokens ----------------
__global__ __launch_bounds__(256) void mean50(const float* __restrict__ h2,
                                              float* __restrict__ g) {
    int b = blockIdx.x, c = threadIdx.x;
    float s = 0.f;
    for (int n = 0; n < NTOK; ++n) s += h2[((size_t)b * NTOK + n) * C_DIM + c];
    g[(size_t)b * C_DIM + c] = s / 50.0f;
}

// ---------------- pred = tanh(h3 @ w2): one wave per row ----------------
__global__ __launch_bounds__(256) void matvec_tanh(const float* __restrict__ h3,
                                                   const float* __restrict__ w2,
                                                   float* __restrict__ pred) {
    int row  = blockIdx.x * 4 + (threadIdx.x >> 6);
    int lane = threadIdx.x & 63;
    const float* rp = h3 + (size_t)row * C_DIM;
    float4 a = *(const float4*)(rp + lane * 4);
    float4 w = *(const float4*)(w2 + lane * 4);
    float s = a.x * w.x + a.y * w.y + a.z * w.z + a.w * w.w;
#pragma unroll
    for (int off = 32; off; off >>= 1) s += __shfl_xor(s, off);
    if (lane == 0) pred[row] = tanhf(s);
}

// ---------------- JAX threefry2x32 with key (0,1)  [jax.random.key(1)] ----------------
__device__ __forceinline__ uint32_t rotl32(uint32_t x, int r) {
    return (x << r) | (x >> (32 - r));
}
__device__ __forceinline__ void threefry01(uint32_t& x0, uint32_t& x1) {
    const uint32_t ks0 = 0u, ks1 = 1u, ks2 = 0x1BD11BDBu; // 0^1^0x1BD11BDA
    x0 += ks0; x1 += ks1;
#define TFR(r) { x0 += x1; x1 = rotl32(x1, r); x1 ^= x0; }
    TFR(13) TFR(15) TFR(26) TFR(6)  x0 += ks1; x1 += ks2 + 1u;
    TFR(17) TFR(29) TFR(16) TFR(24) x0 += ks2; x1 += ks0 + 2u;
    TFR(13) TFR(15) TFR(26) TFR(6)  x0 += ks0; x1 += ks1 + 3u;
    TFR(17) TFR(29) TFR(16) TFR(24) x0 += ks1; x1 += ks2 + 4u;
    TFR(13) TFR(15) TFR(26) TFR(6)  x0 += ks2; x1 += ks0 + 5u;
#undef TFR
}

// XLA/Giles single-precision erfinv
__device__ __forceinline__ float erfinv_xla(float x) {
    float w = -log1pf(-x * x);
    float p;
    if (w < 5.0f) {
        w -= 2.5f;
        p = 2.81022636e-08f;
        p = fmaf(p, w, 3.43273939e-07f);
        p = fmaf(p, w, -3.5233877e-06f);
        p = fmaf(p, w, -4.39150654e-06f);
        p = fmaf(p, w, 0.00021858087f);
        p = fmaf(p, w, -0.00125372503f);
        p = fmaf(p, w, -0.00417768164f);
        p = fmaf(p, w, 0.246640727f);
        p = fmaf(p, w, 1.50140941f);
    } else {
        w = sqrtf(w) - 3.0f;
        p = -0.000200214257f;
        p = fmaf(p, w, 0.000100950558f);
        p = fmaf(p, w, 0.00134934322f);
        p = fmaf(p, w, -0.00367342844f);
        p = fmaf(p, w, 0.00573950773f);
        p = fmaf(p, w, -0.0076224613f);
        p = fmaf(p, w, 0.00943887047f);
        p = fmaf(p, w, 1.00167406f);
        p = fmaf(p, w, 2.83297682f);
    }
    return p * x;
}

__device__ __forceinline__ float bits_to_normal(uint32_t bits) {
    // uniform in [-1+2^-24, 1): mantissa trick, scale=(1-lo) rounds to 2.0f, sqrt2*erfinv
    float f = __uint_as_float((bits >> 9) | 0x3f800000u) - 1.0f;
    float u = f * 2.0f + (-0.99999994039535522461f);
    u = fmaxf(-0.99999994039535522461f, u);
    return 1.4142135623730951f * erfinv_xla(u);
}

// stable top-12 of 48 + ascending-index position, accumulate counts
__device__ __forceinline__ void do_topk(float v, int lane, int b, int* __restrict__ counts) {
    int rank = 0;
#pragma unroll
    for (int e = 0; e < NSPA; ++e) {
        float ve = __shfl(v, e);
        rank += (ve > v || (ve == v && e < lane)) ? 1 : 0;
    }
    bool sel = (lane < NSPA) && (rank < TOPKK);
    unsigned long long mask = __ballot(sel);
    if (sel) {
        int kpos = __popcll(mask & ((1ull << lane) - 1ull));
        atomicAdd(&counts[((size_t)b * TOPKK + kpos) * NSPA + lane], 1);
    }
}

// Partitionable threefry (modern JAX default): element i <- threefry(key, (i>>32, i&0xffffffff)),
// 32-bit output = out0 ^ out1. One wave per (b, s) sample; lane = spatial position.
__global__ __launch_bounds__(256) void topk_kernel(const float* __restrict__ pred,
                                                   int* __restrict__ counts) {
    int wid  = (blockIdx.x * 256 + threadIdx.x) >> 6;  // 0..95999 = b*500 + s
    int lane = threadIdx.x & 63;
    int b = wid / NSAMP;
    int s = wid - b * NSAMP;
    uint32_t lo = (uint32_t)((b * NSAMP + s) * NSPA + lane);  // 64-bit idx < 2^32 -> hi = 0
    uint32_t x0 = 0u, x1 = lo;
    threefry01(x0, x1);
    float n = bits_to_normal(x0 ^ x1);
    float sc = (lane < NSPA) ? pred[b * NTOK + 2 + lane] : 0.f;
    float v  = (lane < NSPA) ? sc + n * 0.05f : -INFINITY;
    do_topk(v, lane, b, counts);
}

// ---------------- output assembly ----------------
__global__ __launch_bounds__(256) void select_out(const float* __restrict__ x,
                                                  const int* __restrict__ counts,
                                                  float* __restrict__ out) {
    int row = blockIdx.x;            // 0..2687 = b*14 + k
    int b = row / 14, k = row - b * 14;
    int d = threadIdx.x;             // 0..255; handles d and d+256
    if (k < 2) {
        out[(size_t)row * D_EMB + d]       = x[((size_t)(b * NTOK + k)) * D_EMB + d];
        out[(size_t)row * D_EMB + d + 256] = x[((size_t)(b * NTOK + k)) * D_EMB + d + 256];
    } else {
        int kk = k - 2;
        const int* cnt = counts + ((size_t)b * TOPKK + kk) * NSPA;
        __shared__ int sc[NSPA];
        if (d < NSPA) sc[d] = cnt[d];
        __syncthreads();
        float a0 = 0.f, a1 = 0.f;
        for (int l = 0; l < NSPA; ++l) {
            int c = sc[l];
            if (c) {
                float w = (float)c / 500.0f;
                const float* xr = x + ((size_t)(b * NTOK + 2 + l)) * D_EMB;
                a0 = fmaf(w, xr[d], a0);
                a1 = fmaf(w, xr[d + 256], a1);
            }
        }
        out[(size_t)row * D_EMB + d]       = a0;
        out[(size_t)row * D_EMB + d + 256] = a1;
    }
}

extern "C" void kernel_launch(void* const* d_in, const int* in_sizes, int n_in,
                              void* d_out, int out_size, void* d_ws, size_t ws_size,
                              hipStream_t stream) {
    const float* x    = (const float*)d_in[0];
    const float* ln_g = (const float*)d_in[1];
    const float* ln_b = (const float*)d_in[2];
    const float* w_in = (const float*)d_in[3];
    const float* wq   = (const float*)d_in[4];
    const float* wk   = (const float*)d_in[5];
    const float* wv   = (const float*)d_in[6];
    const float* wo   = (const float*)d_in[7];
    const float* w1   = (const float*)d_in[8];
    const float* w2   = (const float*)d_in[9];
    float* out = (float*)d_out;

    float* ws = (float*)d_ws;
    float* xn    = ws;                               // 9600*512
    float* h1    = xn + (size_t)ROWS * D_EMB;        // 9600*256
    float* q     = h1 + (size_t)ROWS * C_DIM;
    float* k     = q  + (size_t)ROWS * C_DIM;
    float* v     = k  + (size_t)ROWS * C_DIM;
    float* ao    = v  + (size_t)ROWS * C_DIM;
    float* gmean = ao + (size_t)ROWS * C_DIM;        // 192*256
    float* gw    = gmean + (size_t)B2 * C_DIM;       // 192*256
    float* pred  = gw + (size_t)B2 * C_DIM;          // 9600
    int*   counts = (int*)(pred + ROWS);             // 192*12*48 ints
    float* h2 = q;   // q dead after attention
    float* h3 = k;   // k dead after attention

    ln_kernel<<<ROWS / 4, 256, 0, stream>>>(x, ln_g, ln_b, xn);
    gemm_f32<<<dim3(ROWS / 64, C_DIM / 64), 256, 0, stream>>>(xn, w_in, h1, ROWS, C_DIM, D_EMB, nullptr, 1);
    gemm_f32<<<dim3(ROWS / 64, C_DIM / 64), 256, 0, stream>>>(h1, wq, q, ROWS, C_DIM, C_DIM, nullptr, 0);
    gemm_f32<<<dim3(ROWS / 64, C_DIM / 64), 256, 0, stream>>>(h1, wk, k, ROWS, C_DIM, C_DIM, nullptr, 0);
    gemm_f32<<<dim3(ROWS / 64, C_DIM / 64), 256, 0, stream>>>(h1, wv, v, ROWS, C_DIM, C_DIM, nullptr, 0);
    attn_kernel<<<B2 * 2, 256, 0, stream>>>(q, k, v, ao);
    gemm_f32<<<dim3(ROWS / 64, C_DIM / 64), 256, 0, stream>>>(ao, wo, h2, ROWS, C_DIM, C_DIM, nullptr, 0);
    mean50<<<B2, 256, 0, stream>>>(h2, gmean);
    gemm_f32<<<dim3(B2 / 64, C_DIM / 64), 256, 0, stream>>>(gmean, w1 + (size_t)C_DIM * C_DIM, gw, B2, C_DIM, C_DIM, nullptr, 0);
    gemm_f32<<<dim3(ROWS / 64, C_DIM / 64), 256, 0, stream>>>(h2, w1, h3, ROWS, C_DIM, C_DIM, gw, 1);
    matvec_tanh<<<ROWS / 4, 256, 0, stream>>>(h3, w2, pred);
    hipMemsetAsync(counts, 0, (size_t)B2 * TOPKK * NSPA * sizeof(int), stream);
    topk_kernel<<<B2 * NSAMP / 4, 256, 0, stream>>>(pred, counts);
    select_out<<<B2 * 14, 256, 0, stream>>>(x, counts, out);
}